// Round 1
// baseline (2303.191 us; speedup 1.0000x reference)
//
#include <hip/hip_runtime.h>
#include <math.h>

#define BATCH 524288
#define DIN 118

__device__ __forceinline__ float fast_tanh(float v) {
    float a = fabsf(v);
    float e = __expf(-2.0f * a);
    float t = 1.0f - 2.0f * e / (1.0f + e);
    return copysignf(t, v);
}

__global__ __launch_bounds__(256) void fwd_kernel(
    const float* __restrict__ x,
    const float* __restrict__ eW0, const float* __restrict__ eb0,
    const float* __restrict__ eW1, const float* __restrict__ eb1,
    const float* __restrict__ eW2, const float* __restrict__ eb2,
    const float* __restrict__ eW3, const float* __restrict__ eb3,
    const float* __restrict__ dW0, const float* __restrict__ db0,
    const float* __restrict__ dW1, const float* __restrict__ db1,
    const float* __restrict__ dW2, const float* __restrict__ db2,
    const float* __restrict__ dW3, const float* __restrict__ db3,
    const float* __restrict__ tW0, const float* __restrict__ tb0,
    const float* __restrict__ tW1, const float* __restrict__ tb1,
    float* __restrict__ dec_out, float* __restrict__ zbuf,
    double* __restrict__ acc)
{
    const int b = blockIdx.x * blockDim.x + threadIdx.x;
    const float2* __restrict__ xr = (const float2*)(x + (size_t)b * DIN);

    // ---- encoder layer 0 (118 -> 60), streaming x, accumulate x stats ----
    float h[60];
    #pragma unroll
    for (int j = 0; j < 60; ++j) h[j] = eb0[j];
    float sx = 0.f, sx2 = 0.f;
    #pragma unroll 1
    for (int ib = 0; ib < 59; ++ib) {
        float2 xv = xr[ib];
        sx += xv.x + xv.y;
        sx2 = fmaf(xv.x, xv.x, fmaf(xv.y, xv.y, sx2));
        const float* __restrict__ w0 = eW0 + (2 * ib) * 60;
        const float* __restrict__ w1 = w0 + 60;
        #pragma unroll
        for (int j = 0; j < 60; ++j)
            h[j] = fmaf(xv.x, w0[j], fmaf(xv.y, w1[j], h[j]));
    }
    #pragma unroll
    for (int j = 0; j < 60; ++j) h[j] = fmaxf(h[j], 0.f);

    // ---- encoder layer 1 (60 -> 30) relu ----
    float h2[30];
    #pragma unroll
    for (int j = 0; j < 30; ++j) {
        float a = eb1[j];
        #pragma unroll
        for (int i = 0; i < 60; ++i) a = fmaf(h[i], eW1[i * 30 + j], a);
        h2[j] = fmaxf(a, 0.f);
    }
    // ---- encoder layer 2 (30 -> 10) relu ----
    float h3[10];
    #pragma unroll
    for (int j = 0; j < 10; ++j) {
        float a = eb2[j];
        #pragma unroll
        for (int i = 0; i < 30; ++i) a = fmaf(h2[i], eW2[i * 10 + j], a);
        h3[j] = fmaxf(a, 0.f);
    }
    // ---- encoder layer 3 (10 -> 1) linear ----
    float enc = eb3[0];
    #pragma unroll
    for (int i = 0; i < 10; ++i) enc = fmaf(h3[i], eW3[i], enc);

    // ---- decoder layer 0 (1 -> 10) tanh ----
    float g1[10];
    #pragma unroll
    for (int j = 0; j < 10; ++j) g1[j] = fast_tanh(fmaf(enc, dW0[j], db0[j]));
    // ---- decoder layer 1 (10 -> 30) tanh ----
    float g2[30];
    #pragma unroll
    for (int j = 0; j < 30; ++j) {
        float a = db1[j];
        #pragma unroll
        for (int i = 0; i < 10; ++i) a = fmaf(g1[i], dW1[i * 30 + j], a);
        g2[j] = fast_tanh(a);
    }
    // ---- decoder layer 2 (30 -> 60) tanh ----
    float g3[60];
    #pragma unroll
    for (int j = 0; j < 60; ++j) {
        float a = db2[j];
        #pragma unroll
        for (int i = 0; i < 30; ++i) a = fmaf(g2[i], dW2[i * 60 + j], a);
        g3[j] = fast_tanh(a);
    }
    // ---- decoder layer 3 (60 -> 118), streamed outputs + re-read x ----
    float dotxd = 0.f, sd2 = 0.f, sdf2 = 0.f;
    float2* __restrict__ orow = (float2*)(dec_out + (size_t)b * DIN);
    #pragma unroll 1
    for (int ob = 0; ob < 59; ++ob) {
        float2 xv = xr[ob];
        float a0 = db3[2 * ob];
        float a1 = db3[2 * ob + 1];
        const float* __restrict__ wc = dW3 + 2 * ob;
        #pragma unroll
        for (int i = 0; i < 60; ++i) {
            a0 = fmaf(g3[i], wc[i * 118 + 0], a0);
            a1 = fmaf(g3[i], wc[i * 118 + 1], a1);
        }
        dotxd = fmaf(xv.x, a0, fmaf(xv.y, a1, dotxd));
        sd2 = fmaf(a0, a0, fmaf(a1, a1, sd2));
        float u0 = xv.x - a0, u1 = xv.y - a1;
        sdf2 = fmaf(u0, u0, fmaf(u1, u1, sdf2));
        orow[ob] = make_float2(a0, a1);
    }

    // ---- z features ----
    float xn = sqrtf(sx2);
    float dn = sqrtf(sd2);
    float rel = sqrtf(sdf2) / fmaxf(xn, 1e-10f);
    float cs = dotxd / fmaxf(xn * dn, 1e-10f);
    float mean = sx * (1.0f / DIN);
    float var = fmaxf(sx2 * (1.0f / DIN) - mean * mean, 0.f);
    float stdv = sqrtf(var);
    float zc[4] = {enc, rel, cs, stdv};
    ((float4*)zbuf)[b] = make_float4(zc[0], zc[1], zc[2], zc[3]);

    // ---- estimation net (4 -> 10 tanh -> 2) + softmax ----
    float l0 = tb1[0], l1 = tb1[1];
    #pragma unroll
    for (int j = 0; j < 10; ++j) {
        float a = tb0[j];
        #pragma unroll
        for (int c = 0; c < 4; ++c) a = fmaf(zc[c], tW0[c * 10 + j], a);
        float t = fast_tanh(a);
        l0 = fmaf(t, tW1[j * 2 + 0], l0);
        l1 = fmaf(t, tW1[j * 2 + 1], l1);
    }
    float lm = fmaxf(l0, l1);
    float e0 = __expf(l0 - lm), e1 = __expf(l1 - lm);
    float inv = 1.0f / (e0 + e1);
    float gam[2] = {e0 * inv, e1 * inv};

    // ---- GMM moment accumulation in fp64: per k: [Sg, S1(4), S2sym(10)] ----
    double vals[30];
    {
        int idx = 0;
        #pragma unroll
        for (int k = 0; k < 2; ++k) {
            double g = (double)gam[k];
            vals[idx++] = g;
            double gz[4];
            #pragma unroll
            for (int c = 0; c < 4; ++c) { gz[c] = g * (double)zc[c]; vals[idx++] = gz[c]; }
            #pragma unroll
            for (int c = 0; c < 4; ++c) {
                #pragma unroll
                for (int d = c; d < 4; ++d) vals[idx++] = gz[c] * (double)zc[d];
            }
        }
    }
    #pragma unroll
    for (int i = 0; i < 30; ++i) {
        double v = vals[i];
        #pragma unroll
        for (int off = 32; off > 0; off >>= 1) v += __shfl_down(v, off);
        if ((threadIdx.x & 63) == 0) atomicAdd(&acc[i], v);
    }
}

__global__ __launch_bounds__(64) void gmm_kernel(
    const double* __restrict__ acc, const float* __restrict__ zbuf,
    float* __restrict__ params, float* __restrict__ covdiag_out)
{
    if (threadIdx.x != 0) return;
    const double TWO_PI = 6.283185307179586;
    double covdiag_sum = 0.0;
    double mu_all[2][4], R_all[2][4], c_all[2];
    for (int k = 0; k < 2; ++k) {
        const double* a = acc + k * 15;
        double Sg = a[0];
        double mu[4];
        for (int c = 0; c < 4; ++c) mu[c] = a[1 + c] / Sg;
        double M[4][4];
        int idx = 5;
        for (int c = 0; c < 4; ++c)
            for (int d = c; d < 4; ++d) {
                double v = a[idx++] / Sg - mu[c] * mu[d];
                M[c][d] = v; M[d][c] = v;
            }
        for (int c = 0; c < 4; ++c) M[c][c] += 1e-12;
        for (int c = 0; c < 4; ++c) covdiag_sum += 1.0 / M[c][c];
        // Gauss-Jordan inverse with partial pivoting; det from pivots
        double A[4][4], inv4[4][4];
        for (int r = 0; r < 4; ++r)
            for (int c = 0; c < 4; ++c) { A[r][c] = M[r][c]; inv4[r][c] = (r == c) ? 1.0 : 0.0; }
        double det = 1.0;
        for (int col = 0; col < 4; ++col) {
            int piv = col;
            for (int r = col + 1; r < 4; ++r)
                if (fabs(A[r][col]) > fabs(A[piv][col])) piv = r;
            if (piv != col) {
                for (int c = 0; c < 4; ++c) {
                    double t = A[col][c]; A[col][c] = A[piv][c]; A[piv][c] = t;
                    t = inv4[col][c]; inv4[col][c] = inv4[piv][c]; inv4[piv][c] = t;
                }
                det = -det;
            }
            double p = A[col][col];
            det *= p;
            double ip = 1.0 / p;
            for (int c = 0; c < 4; ++c) { A[col][c] *= ip; inv4[col][c] *= ip; }
            for (int r = 0; r < 4; ++r) if (r != col) {
                double f = A[r][col];
                for (int c = 0; c < 4; ++c) { A[r][c] -= f * A[col][c]; inv4[r][c] -= f * inv4[col][c]; }
            }
        }
        double det_cov = det * TWO_PI * TWO_PI * TWO_PI * TWO_PI;
        double phi = Sg / (double)BATCH;
        c_all[k] = phi / (sqrt(det_cov) + 1e-12);
        for (int g = 0; g < 4; ++g) {
            R_all[k][g] = inv4[g][0] + inv4[g][1] + inv4[g][2] + inv4[g][3];
            mu_all[k][g] = mu[g];
        }
    }
    // max_val quirk: from sample 0 only
    float4 z0 = *(const float4*)zbuf;
    double z0d[4] = {z0.x, z0.y, z0.z, z0.w};
    double mv = 0.0;
    for (int k = 0; k < 2; ++k) {
        double t = 0.0, inr = 0.0;
        for (int g = 0; g < 4; ++g) {
            double d = z0d[g] - mu_all[k][g];
            t += d; inr += d * R_all[k][g];
        }
        double e = -0.5 * inr * t;
        if (e > mv) mv = e;
    }
    for (int k = 0; k < 2; ++k) {
        for (int g = 0; g < 4; ++g) {
            params[k * 9 + g] = (float)mu_all[k][g];
            params[k * 9 + 4 + g] = (float)R_all[k][g];
        }
        params[k * 9 + 8] = (float)c_all[k];
    }
    params[18] = (float)mv;
    covdiag_out[0] = (float)covdiag_sum;
}

__global__ __launch_bounds__(256) void energy_kernel(
    const float4* __restrict__ zbuf, const float* __restrict__ params,
    float* __restrict__ energy_out)
{
    int b = blockIdx.x * blockDim.x + threadIdx.x;
    float4 z = zbuf[b];
    float mv = params[18];
    float s = 0.f;
    #pragma unroll
    for (int k = 0; k < 2; ++k) {
        const float* p = params + k * 9;
        float d0 = z.x - p[0], d1 = z.y - p[1], d2 = z.z - p[2], d3 = z.w - p[3];
        float t = d0 + d1 + d2 + d3;
        float inr = d0 * p[4] + d1 * p[5] + d2 * p[6] + d3 * p[7];
        float e = -0.5f * inr * t - mv;
        e = fminf(fmaxf(e, -50.f), 50.f);
        s = fmaf(p[8], __expf(e), s);
    }
    energy_out[b] = -mv - __logf(s + 1e-12f);
}

extern "C" void kernel_launch(void* const* d_in, const int* in_sizes, int n_in,
                              void* d_out, int out_size, void* d_ws, size_t ws_size,
                              hipStream_t stream) {
    const float* x   = (const float*)d_in[0];
    const float* eW0 = (const float*)d_in[1];
    const float* eb0 = (const float*)d_in[2];
    const float* eW1 = (const float*)d_in[3];
    const float* eb1 = (const float*)d_in[4];
    const float* eW2 = (const float*)d_in[5];
    const float* eb2 = (const float*)d_in[6];
    const float* eW3 = (const float*)d_in[7];
    const float* eb3 = (const float*)d_in[8];
    const float* dW0 = (const float*)d_in[9];
    const float* db0 = (const float*)d_in[10];
    const float* dW1 = (const float*)d_in[11];
    const float* db1 = (const float*)d_in[12];
    const float* dW2 = (const float*)d_in[13];
    const float* db2 = (const float*)d_in[14];
    const float* dW3 = (const float*)d_in[15];
    const float* db3 = (const float*)d_in[16];
    const float* tW0 = (const float*)d_in[17];
    const float* tb0 = (const float*)d_in[18];
    const float* tW1 = (const float*)d_in[19];
    const float* tb1 = (const float*)d_in[20];

    float* out = (float*)d_out;
    float* dec_out = out;                              // [B,118]
    float* energy_out = out + (size_t)BATCH * DIN;     // [B]
    float* covdiag_out = out + (size_t)BATCH * (DIN + 1); // scalar

    char* ws = (char*)d_ws;
    float* zbuf = (float*)ws;                                  // B * 4 floats
    double* acc = (double*)(ws + (size_t)BATCH * 16);          // 30 doubles
    float* params = (float*)(ws + (size_t)BATCH * 16 + 512);   // 19 floats

    hipMemsetAsync(acc, 0, 30 * sizeof(double), stream);

    dim3 block(256);
    dim3 grid(BATCH / 256);
    fwd_kernel<<<grid, block, 0, stream>>>(
        x, eW0, eb0, eW1, eb1, eW2, eb2, eW3, eb3,
        dW0, db0, dW1, db1, dW2, db2, dW3, db3,
        tW0, tb0, tW1, tb1, dec_out, zbuf, acc);
    gmm_kernel<<<1, 64, 0, stream>>>(acc, zbuf, params, covdiag_out);
    energy_kernel<<<grid, block, 0, stream>>>((const float4*)zbuf, params, energy_out);
}